// Round 12
// baseline (165.987 us; speedup 1.0000x reference)
//
#include <hip/hip_runtime.h>
#include <cmath>

#define NDEV   100000
#define NBATCH 8192
#define CONTF  62
#define EMB    16
#define FEAT   94      // 62 + 16 + 16
#define KNBR   64
#define NH     4
#define OUTD   16
#define HOUT   64      // NH*OUTD
#define FUS    204     // 94 + 94 + 16
#define ALPHA  0.2f

#define NDEVG2  782    // ceil(100000/128) row-groups
#define NCOMBG2 64     // 8192/128 row-groups
#define KP      48     // K-pairs incl. zero pad (96 bf16 = 48 uints)

typedef unsigned short ushortT;
typedef unsigned int   uintT;
typedef ushortT ushort8v __attribute__((ext_vector_type(8)));
typedef short   short8  __attribute__((ext_vector_type(8)));
typedef float   float4v __attribute__((ext_vector_type(4)));

// ---------------- workspace layout (float slots) ----------------
// h_bf  : NDEV*64 bf16 = 3,200,000 @ 0   (12.8 MB)
// e_d   : NDEV*4       =   400,000 @ 3,200,000
// e_c   : NBATCH*4     =    32,768 @ 3,600,000
// wpack : 2*64*48 uint =     6,144 @ 3,632,768   (bf16x2-packed W^T, dev|comb)

template <typename T>
__device__ __forceinline__ const T* uniform_ptr(const T* p) {
  uint64_t v = (uint64_t)(uintptr_t)p;
  uint32_t lo = __builtin_amdgcn_readfirstlane((uint32_t)v);
  uint32_t hi = __builtin_amdgcn_readfirstlane((uint32_t)(v >> 32));
  return (const T*)(uintptr_t)(((uint64_t)hi << 32) | lo);
}

__device__ __forceinline__ float bf2f(ushortT u) {
  return __uint_as_float(((unsigned int)u) << 16);
}
__device__ __forceinline__ ushortT f2bf(float f) {
  unsigned int i = __float_as_uint(f);
  unsigned int r = i + 0x7FFFu + ((i >> 16) & 1u);  // round-to-nearest-even
  return (ushortT)(r >> 16);
}
__device__ __forceinline__ uintT pack2(float lo, float hi) {
  return ((uintT)f2bf(hi) << 16) | (uintT)f2bf(lo);
}

union FragU { uint4 u; short8 s; };

// ---------------- K0: pack W^T -> bf16x2 once (layout [n][p], n=h*16+o) -----
__global__ __launch_bounds__(256) void k_prep(
    const float* __restrict__ Wd, const float* __restrict__ Wc,
    uintT* __restrict__ wpack) {
  const int e = blockIdx.x * 256 + threadIdx.x;   // 0..6143
  if (e >= 2 * 64 * KP) return;
  const bool dev = e < 64 * KP;
  const int i = dev ? e : e - 64 * KP;
  const int n = i / KP, p = i - n * KP;
  const int h = n >> 4, o = n & 15;
  const float* __restrict__ Ws = dev ? Wd : Wc;
  uintT v = 0u;
  if (p < 47) {
    const float lo = Ws[(h * FEAT + 2 * p) * OUTD + o];
    const float hi = Ws[(h * FEAT + 2 * p + 1) * OUTD + o];
    v = pack2(lo, hi);
  }
  wpack[e] = v;
}

// ---------------- K1: X[row,94] @ W[94,64] via bf16 MFMA, 128 rows/block ----
__global__ __launch_bounds__(256, 2) void k_feat(
    const float* __restrict__ device_cont, const int* __restrict__ device_cat,
    const float* __restrict__ de0, const float* __restrict__ de1,
    const float* __restrict__ bd,
    const float* __restrict__ combin_cont, const int* __restrict__ combin_cat,
    const int* __restrict__ combin_idx,
    const float* __restrict__ ce0, const float* __restrict__ ce1,
    const float* __restrict__ bc,
    const float* __restrict__ aW, const uintT* __restrict__ wpack,
    ushortT* __restrict__ h_bf, float* __restrict__ e_d, float* __restrict__ e_c) {
  __shared__ uintT x_s[128 * KP];  // 24,576 B  [row][kpair]
  __shared__ uintT w_s[64 * KP];   // 12,288 B  [col n][kpair]
  __shared__ int   ci_s[128];

  const int tid  = threadIdx.x;
  const int lane = tid & 63;
  const int wv = __builtin_amdgcn_readfirstlane((int)(tid >> 6));
  const int blk = blockIdx.x;
  const bool devp = blk < NDEVG2;
  const int b0 = (devp ? blk : blk - NDEVG2) * 128;

  if (!devp && tid < 128) ci_s[tid] = combin_idx[b0 + tid];

  // ---- stage W: linear uint4 copy of the prepacked slab (768 uint4) ----
  {
    const uint4* __restrict__ wp =
        reinterpret_cast<const uint4*>(wpack + (devp ? 0 : 64 * KP));
#pragma unroll
    for (int t = 0; t < 3; ++t)
      reinterpret_cast<uint4*>(w_s)[t * 256 + tid] = wp[t * 256 + tid];
  }
  __syncthreads();  // ci_s visible

  // ---- stage x: cont pairs (128*31 = 3968) ----
  {
    const float* __restrict__ cont = devp ? device_cont : combin_cont;
#pragma unroll 1
    for (int e = tid; e < 128 * 31; e += 256) {
      const int r = e / 31, p = e - r * 31;
      const size_t srow = devp ? (size_t)min(b0 + r, NDEV - 1) : (size_t)ci_s[r];
      const float2 v = *reinterpret_cast<const float2*>(cont + srow * CONTF + 2 * p);
      x_s[r * KP + p] = pack2(v.x, v.y);
    }
  }
  // ---- stage embeddings: all 256 threads, one (row, table) each ----
  {
    const int r = tid >> 1, tb = tid & 1;  // r in 0..127
    const int srow = devp ? min(b0 + r, NDEV - 1) : ci_s[r];
    const int cidx = (devp ? device_cat : combin_cat)[2 * srow + tb];
    const float* __restrict__ ep =
        (tb ? (devp ? de1 : ce1) : (devp ? de0 : ce0)) + (size_t)cidx * EMB;
    uintT* __restrict__ dst = &x_s[r * KP + 31 + tb * 8];
#pragma unroll
    for (int k4 = 0; k4 < 4; ++k4) {
      const float4 v = reinterpret_cast<const float4*>(ep)[k4];
      dst[2 * k4 + 0] = pack2(v.x, v.y);
      dst[2 * k4 + 1] = pack2(v.z, v.w);
    }
  }
  if (tid < 128) x_s[tid * KP + 47] = 0u;         // k = 94,95 zero pad
  __syncthreads();

  // ---- MFMA compute ----
  const int m = lane & 15, q = lane >> 4;
  const float* bias = uniform_ptr(devp ? bd : bc);
  const float* aWl  = uniform_ptr(aW);

  float4v acc[2][NH];
#pragma unroll
  for (int ct = 0; ct < NH; ++ct) {
    const float bv = bias[ct * OUTD + m];
    acc[0][ct] = (float4v){bv, bv, bv, bv};
    acc[1][ct] = (float4v){bv, bv, bv, bv};
  }

  const uintT* xa0 = &x_s[(wv * 16 + m) * KP + q * 4];
  const uintT* xa1 = &x_s[(64 + wv * 16 + m) * KP + q * 4];
#pragma unroll
  for (int c = 0; c < 3; ++c) {                  // K chunks of 32
    FragU af0, af1;
    af0.u = *reinterpret_cast<const uint4*>(xa0 + c * 16);
    af1.u = *reinterpret_cast<const uint4*>(xa1 + c * 16);
#pragma unroll
    for (int ct = 0; ct < NH; ++ct) {
      FragU bf;
      bf.u = *reinterpret_cast<const uint4*>(&w_s[(ct * 16 + m) * KP + c * 16 + q * 4]);
      acc[0][ct] = __builtin_amdgcn_mfma_f32_16x16x32_bf16(af0.s, bf.s, acc[0][ct], 0, 0, 0);
      acc[1][ct] = __builtin_amdgcn_mfma_f32_16x16x32_bf16(af1.s, bf.s, acc[1][ct], 0, 0, 0);
    }
  }

  // ---- epilogue: e logits + h store, per row-tile ----
  const int aoff = devp ? OUTD : 0;
  float* __restrict__ eout = devp ? e_d : e_c;
#pragma unroll
  for (int rt = 0; rt < 2; ++rt) {
    const int rowq = b0 + rt * 64 + wv * 16 + q * 4;  // first of 4 rows
#pragma unroll
    for (int ct = 0; ct < NH; ++ct) {
      const float av = aWl[ct * 2 * OUTD + aoff + m];
      float e0 = acc[rt][ct][0] * av, e1 = acc[rt][ct][1] * av,
            e2 = acc[rt][ct][2] * av, e3 = acc[rt][ct][3] * av;
#pragma unroll
      for (int msk = 1; msk < 16; msk <<= 1) {
        e0 += __shfl_xor(e0, msk);
        e1 += __shfl_xor(e1, msk);
        e2 += __shfl_xor(e2, msk);
        e3 += __shfl_xor(e3, msk);
      }
      if (m == ct) {
        const float ev[4] = {e0, e1, e2, e3};
#pragma unroll
        for (int r = 0; r < 4; ++r)
          if (!devp || rowq + r < NDEV) eout[(size_t)(rowq + r) * NH + ct] = ev[r];
      }
    }
    if (devp) {
#pragma unroll
      for (int ct = 0; ct < NH; ++ct) {
#pragma unroll
        for (int r = 0; r < 4; ++r) {
          if (rowq + r < NDEV)
            h_bf[(size_t)(rowq + r) * HOUT + ct * OUTD + m] = f2bf(acc[rt][ct][r]);
        }
      }
    }
  }
}

// ---------------- K2: attention + fusion + MLP, 2 rows per wave -------------
// W2 is 52 KB (doesn't fit L1); loading it once per wave for TWO rows halves
// the dominant L2 stream (427 -> 213 MB). All LDS per-wave; wave_barrier only.
__global__ __launch_bounds__(256, 4) void k_attn(
    const int* __restrict__ neighbor_idx, const int* __restrict__ device_idx,
    const int* __restrict__ device_cat, const float* __restrict__ device_cont,
    const float* __restrict__ de0, const float* __restrict__ de1,
    const int* __restrict__ combin_idx, const int* __restrict__ combin_cat,
    const float* __restrict__ combin_cont,
    const float* __restrict__ ce0, const float* __restrict__ ce1,
    const ushortT* __restrict__ h_bf, const float* __restrict__ e_d,
    const float* __restrict__ e_c, const float* __restrict__ ab,
    const float* __restrict__ W1, const float* __restrict__ b1,
    const float* __restrict__ W2, const float* __restrict__ b2,
    const float* __restrict__ W3, const float* __restrict__ b3,
    const float* __restrict__ W4, const float* __restrict__ b4,
    float* __restrict__ out) {
  __shared__ __align__(16) float pb[4][2][NH][68];   // 8704 B
  __shared__ __align__(16) int   nb[4][2][KNBR];     // 2048 B
  __shared__ __align__(16) float hb[4][2][HOUT];     // 2048 B
  __shared__ __align__(16) float fusb[4][2][208];    // 6656 B
  __shared__ __align__(16) float x1b[4][2][64];      // 2048 B

  const int lane = threadIdx.x & 63;
  const int wid  = __builtin_amdgcn_readfirstlane((int)(threadIdx.x >> 6));
  const int r0   = blockIdx.x * 8 + wid * 2;

  // ---- phases A + A2 per row ----
#pragma unroll
  for (int rr = 0; rr < 2; ++rr) {
    const int b = r0 + rr;
    const int nk = neighbor_idx[(size_t)b * KNBR + lane];
    const float4 ed4 = *reinterpret_cast<const float4*>(e_d + (size_t)nk * NH);
    const float4 ec4 = *reinterpret_cast<const float4*>(e_c + (size_t)b * NH);
    const float4 ab4 = *reinterpret_cast<const float4*>(ab);

    float v0 = ec4.x + ed4.x + ab4.x;
    float v1 = ec4.y + ed4.y + ab4.y;
    float v2 = ec4.z + ed4.z + ab4.z;
    float v3 = ec4.w + ed4.w + ab4.w;
    v0 = v0 > 0.f ? v0 : ALPHA * v0;
    v1 = v1 > 0.f ? v1 : ALPHA * v1;
    v2 = v2 > 0.f ? v2 : ALPHA * v2;
    v3 = v3 > 0.f ? v3 : ALPHA * v3;

    float m0 = v0, m1 = v1, m2 = v2, m3 = v3;
#pragma unroll
    for (int msk = 1; msk < 64; msk <<= 1) {
      m0 = fmaxf(m0, __shfl_xor(m0, msk));
      m1 = fmaxf(m1, __shfl_xor(m1, msk));
      m2 = fmaxf(m2, __shfl_xor(m2, msk));
      m3 = fmaxf(m3, __shfl_xor(m3, msk));
    }
    float p0 = expf(v0 - m0), p1 = expf(v1 - m1);
    float p2 = expf(v2 - m2), p3 = expf(v3 - m3);
    float s0 = p0, s1 = p1, s2 = p2, s3 = p3;
#pragma unroll
    for (int msk = 1; msk < 64; msk <<= 1) {
      s0 += __shfl_xor(s0, msk);
      s1 += __shfl_xor(s1, msk);
      s2 += __shfl_xor(s2, msk);
      s3 += __shfl_xor(s3, msk);
    }
    pb[wid][rr][0][lane] = p0 / s0;
    pb[wid][rr][1][lane] = p1 / s1;
    pb[wid][rr][2][lane] = p2 / s2;
    pb[wid][rr][3][lane] = p3 / s3;
    nb[wid][rr][lane]    = nk;

    // fusion features [comb 94 | dev 94]
    const int ci = combin_idx[b];
    const int cc0 = combin_cat[2 * ci], cc1 = combin_cat[2 * ci + 1];
    const int didx = device_idx[b];
    const int dc0 = device_cat[2 * didx], dc1 = device_cat[2 * didx + 1];
#pragma unroll
    for (int t = 0; t < 3; ++t) {
      const int i = lane + t * 64;
      if (i < 188) {
        float v;
        if (i < 62)       v = combin_cont[(size_t)ci * CONTF + i];
        else if (i < 78)  v = ce0[(size_t)cc0 * EMB + (i - 62)];
        else if (i < 94)  v = ce1[(size_t)cc1 * EMB + (i - 78)];
        else if (i < 156) v = device_cont[(size_t)didx * CONTF + (i - 94)];
        else if (i < 172) v = de0[(size_t)dc0 * EMB + (i - 156)];
        else              v = de1[(size_t)dc1 * EMB + (i - 172)];
        fusb[wid][rr][i] = v;
      }
    }
  }
  __builtin_amdgcn_wave_barrier();

  // ---- phase B: h_bf gather, lane = (q, c8), both rows (16 loads in flight)
  {
    const int q = lane >> 3, c8 = lane & 7;
    const int hq = c8 >> 1;
#pragma unroll
    for (int rr = 0; rr < 2; ++rr) {
      float a[8];
#pragma unroll
      for (int i = 0; i < 8; ++i) a[i] = 0.f;
#pragma unroll
      for (int t = 0; t < 8; ++t) {
        const int k   = q * 8 + t;
        const int n   = nb[wid][rr][k];
        const float p = pb[wid][rr][hq][k];
        const ushort8v hv =
            *reinterpret_cast<const ushort8v*>(h_bf + (size_t)n * HOUT + c8 * 8);
#pragma unroll
        for (int i = 0; i < 8; ++i) a[i] = fmaf(p, bf2f(hv[i]), a[i]);
      }
#pragma unroll
      for (int msk = 8; msk < 64; msk <<= 1) {
#pragma unroll
        for (int i = 0; i < 8; ++i) a[i] += __shfl_xor(a[i], msk);
      }
      if (q == 0) {
#pragma unroll
        for (int i = 0; i < 8; ++i) a[i] = a[i] > 0.f ? a[i] : expm1f(a[i]);
        float4* hp = reinterpret_cast<float4*>(&hb[wid][rr][c8 * 8]);
        hp[0] = make_float4(a[0], a[1], a[2], a[3]);
        hp[1] = make_float4(a[4], a[5], a[6], a[7]);
      }
    }
  }
  __builtin_amdgcn_wave_barrier();

  // ---- phase C: attn_feats = head_out(64) @ W1(64x16) + b1 ----
  {
    const int j = lane & 15, gg = lane >> 4;
#pragma unroll
    for (int rr = 0; rr < 2; ++rr) {
      float part = 0.f;
#pragma unroll
      for (int t = 0; t < 16; ++t)
        part = fmaf(hb[wid][rr][gg * 16 + t], W1[(gg * 16 + t) * OUTD + j], part);
      part += __shfl_xor(part, 16);
      part += __shfl_xor(part, 32);
      if (lane < 16) fusb[wid][rr][188 + lane] = part + b1[lane];
    }
  }
  __builtin_amdgcn_wave_barrier();

  // ---- phase D: MLP layer 1 (204 -> 64); W2 value loaded ONCE per 2 rows --
  {
    float a0 = b2[lane], a1 = a0;
#pragma unroll 4
    for (int f = 0; f < FUS; ++f) {
      const float wv = W2[f * 64 + lane];
      a0 = fmaf(fusb[wid][0][f], wv, a0);
      a1 = fmaf(fusb[wid][1][f], wv, a1);
    }
    x1b[wid][0][lane] = fmaxf(a0, 0.f);
    x1b[wid][1][lane] = fmaxf(a1, 0.f);
  }
  __builtin_amdgcn_wave_barrier();

  // ---- layers 2+3 + sigmoid: half-wave per row (no cross-row shuffles!) ----
  const int m = lane & 31, rh = lane >> 5;    // rh = row
  float x2 = b3[m];
#pragma unroll 4
  for (int j = 0; j < 64; ++j)
    x2 = fmaf(x1b[wid][rh][j], W3[j * 32 + m], x2);
  float pL3 = fmaxf(x2, 0.f) * W4[m];
#pragma unroll
  for (int msk = 1; msk < 32; msk <<= 1) pL3 += __shfl_xor(pL3, msk);
  if (m == 0) {
    const float z = pL3 + b4[0];
    out[r0 + rh] = 1.f / (1.f + expf(-z));
  }
}

extern "C" void kernel_launch(void* const* d_in, const int* in_sizes, int n_in,
                              void* d_out, int out_size, void* d_ws, size_t ws_size,
                              hipStream_t stream) {
  const float* combin_cont  = (const float*)d_in[0];
  const int*   combin_cat   = (const int*)d_in[1];
  const float* device_cont  = (const float*)d_in[2];
  const int*   device_cat   = (const int*)d_in[3];
  const int*   combin_idx   = (const int*)d_in[4];
  const int*   device_idx   = (const int*)d_in[5];
  const int*   neighbor_idx = (const int*)d_in[6];
  const float* ce0 = (const float*)d_in[7];
  const float* ce1 = (const float*)d_in[8];
  const float* de0 = (const float*)d_in[9];
  const float* de1 = (const float*)d_in[10];
  const float* Wc  = (const float*)d_in[11];
  const float* bc  = (const float*)d_in[12];
  const float* Wd  = (const float*)d_in[13];
  const float* bd  = (const float*)d_in[14];
  const float* aW  = (const float*)d_in[15];
  const float* ab  = (const float*)d_in[16];
  const float* W1  = (const float*)d_in[17];
  const float* b1  = (const float*)d_in[18];
  const float* W2  = (const float*)d_in[19];
  const float* b2  = (const float*)d_in[20];
  const float* W3  = (const float*)d_in[21];
  const float* b3  = (const float*)d_in[22];
  const float* W4  = (const float*)d_in[23];
  const float* b4  = (const float*)d_in[24];

  float* ws  = (float*)d_ws;
  ushortT* h_bf = (ushortT*)ws;
  float* e_d = ws + 3200000;
  float* e_c = ws + 3600000;
  uintT* wpack = (uintT*)(ws + 3632768);

  k_prep<<<24, 256, 0, stream>>>(Wd, Wc, wpack);
  k_feat<<<NDEVG2 + NCOMBG2, 256, 0, stream>>>(
      device_cont, device_cat, de0, de1, bd,
      combin_cont, combin_cat, combin_idx, ce0, ce1, bc, aW, wpack,
      h_bf, e_d, e_c);
  k_attn<<<1024, 256, 0, stream>>>(
      neighbor_idx, device_idx, device_cat, device_cont, de0, de1,
      combin_idx, combin_cat, combin_cont, ce0, ce1,
      h_bf, e_d, e_c, ab, W1, b1, W2, b2, W3, b3, W4, b4, (float*)d_out);
}